// Round 4
// baseline (30420.312 us; speedup 1.0000x reference)
//
#include <hip/hip_runtime.h>
#include <hip/hip_fp16.h>

#define T_STEPS 512
#define NB      64
#define NI      128
#define NH      256
#define LK      16
#define RS      32
#define NS      (LK + RS)

// ws layout (bytes)
#define WP_OFF    0           // uint4[192*256]: gate weights, k-pair packed 4x half2 (f,i,o,g)
#define VAP8_OFF  786432      // uint4[32*256]: Va^T, 8 consecutive k per entry
#define UAP8_OFF  917504      // uint4[32*256]: Ua^T
#define S1_OFF    1048576     // float[64][2][4][512]: q/ua partials (1 MB)
#define S2_OFF    2097152     // float4[64][2][4][256]: gate partials (2 MB)
#define FLG_OFF   4194304     // int[64][2][2][4]: sync flags
#define LUAH_OFF  5242880     // half[64][32][256]: Ua@long_mem cache (1 MB)
#define WS_NEED   (LUAH_OFF + (size_t)NB * RS * NH * 2)

__device__ __forceinline__ float fsig(float x) {
    return __builtin_amdgcn_rcpf(1.0f + __expf(-x));
}
__device__ __forceinline__ float ftanh(float x) {
    x = fminf(15.0f, fmaxf(-15.0f, x));
    float e = __expf(2.0f * x);
    return (e - 1.0f) * __builtin_amdgcn_rcpf(e + 1.0f);
}
__device__ __forceinline__ float2 h2f(unsigned int u) {
    return __half22float2(*(const __half2*)&u);
}

__global__ void prep_weights(const float* __restrict__ Wf, const float* __restrict__ Wi,
                             const float* __restrict__ Wo, const float* __restrict__ Wg,
                             const float* __restrict__ Ua, const float* __restrict__ Va,
                             unsigned char* __restrict__ ws) {
    int e = blockIdx.x * 256 + threadIdx.x;   // 0..65535
    if (e < 49152) {                          // WP: e = k2*256 + h
        int h = e & 255, k2 = e >> 8, k = 2 * k2;
        uint4 w; __half2 t;
        t = __floats2half2_rn(Wf[h * 384 + k], Wf[h * 384 + k + 1]); w.x = *(unsigned int*)&t;
        t = __floats2half2_rn(Wi[h * 384 + k], Wi[h * 384 + k + 1]); w.y = *(unsigned int*)&t;
        t = __floats2half2_rn(Wo[h * 384 + k], Wo[h * 384 + k + 1]); w.z = *(unsigned int*)&t;
        t = __floats2half2_rn(Wg[h * 384 + k], Wg[h * 384 + k + 1]); w.w = *(unsigned int*)&t;
        ((uint4*)(ws + WP_OFF))[e] = w;
    } else {                                  // Va/Ua 8-k packs
        int e2 = e - 49152;                   // 0..16383
        const float* S = (e2 < 8192) ? Va : Ua;
        int e3 = e2 & 8191;
        int h = e3 & 255, j = e3 >> 8, k = 8 * j;
        uint4 w; __half2 t;
        t = __floats2half2_rn(S[h * 256 + k + 0], S[h * 256 + k + 1]); w.x = *(unsigned int*)&t;
        t = __floats2half2_rn(S[h * 256 + k + 2], S[h * 256 + k + 3]); w.y = *(unsigned int*)&t;
        t = __floats2half2_rn(S[h * 256 + k + 4], S[h * 256 + k + 5]); w.z = *(unsigned int*)&t;
        t = __floats2half2_rn(S[h * 256 + k + 6], S[h * 256 + k + 7]); w.w = *(unsigned int*)&t;
        ((uint4*)(ws + VAP8_OFF))[e2] = w;    // VaP8 then UaP8 contiguous
    }
}

// 4-block group barrier via monotone step-valued flags (release/acquire, agent scope).
__device__ __forceinline__ void group_sync(int* flg4, int r, int t, int tid) {
    __syncthreads();   // drains each wave's vmcnt before barrier -> partials in L2
    if (tid == 0)
        __hip_atomic_store(flg4 + r, t, __ATOMIC_RELEASE, __HIP_MEMORY_SCOPE_AGENT);
    if (tid < 3) {
        int rr = tid + (tid >= r ? 1 : 0);
        while (__hip_atomic_load(flg4 + rr, __ATOMIC_ACQUIRE, __HIP_MEMORY_SCOPE_AGENT) < t)
            __builtin_amdgcn_s_sleep(2);
    }
    __syncthreads();
}

// Grid 256: block = (sample b = blk&63, part r = blk>>6). Partners are 64 apart
// -> same XCD under round-robin dispatch (locality heuristic only; correctness
// is carried by agent-scope release/acquire).
__global__ __launch_bounds__(256, 1) void rel_lstm4(
    const float* __restrict__ x,
    const float* __restrict__ bf_g, const float* __restrict__ bi_g,
    const float* __restrict__ bo_g, const float* __restrict__ bg_g,
    const float* __restrict__ vv_g,
    unsigned char* __restrict__ ws, float* __restrict__ out)
{
    const int tid = threadIdx.x;
    const int blk = blockIdx.x;
    const int b   = blk & 63;
    const int r   = blk >> 6;
    const int h   = tid;

    const uint4* __restrict__ WPp = (const uint4*)(ws + WP_OFF);
    const uint4* __restrict__ VAp = (const uint4*)(ws + VAP8_OFF);
    const uint4* __restrict__ UAp = (const uint4*)(ws + UAP8_OFF);
    float*  __restrict__ S1  = (float*)(ws + S1_OFF);
    float4* __restrict__ S2  = (float4*)(ws + S2_OFF);
    int*    __restrict__ FLG = (int*)(ws + FLG_OFF);
    __half* __restrict__ LUAH = (__half*)(ws + LUAH_OFF) + b * (RS * NH);

    // ---- persistent per-thread weight slices in VGPRs (~256 regs) ----
    uint4 GW[48];          // gates: k2 in [48r, 48r+48) over [st|x] (k = 2*k2)
    uint4 VaW[8], UaW[8];  // Va^T/Ua^T: k in [64r, 64r+64)
#pragma unroll
    for (int j = 0; j < 48; ++j) GW[j] = WPp[(r * 48 + j) * NH + h];
#pragma unroll
    for (int j = 0; j < 8; ++j) { VaW[j] = VAp[(r * 8 + j) * NH + h]; UaW[j] = UAp[(r * 8 + j) * NH + h]; }

    __shared__ __align__(16) float s_inx[NH + NI];   // [st | x]
    __shared__ __align__(16) float s_hid[NH];
    __shared__ float s_q[NH], s_v[NH];
    __shared__ float s_mem[LK][NH];
    __shared__ float s_memua[LK][NH + 4];
    __shared__ __half s_lrawh[RS][NH];               // replicated long raw memory
    __shared__ float s_es[NS], s_al[NS];
    __shared__ float s_scores[T_STEPS];
    __shared__ float s_mask[RS], s_buck[RS];
    __shared__ float s_minv;
    __shared__ int s_minp, s_fill, s_upd, s_pos;

    // ---- init ----
#pragma unroll
    for (int j = 0; j < LK; ++j) { s_mem[j][h] = 0.f; s_memua[j][h] = 0.f; }
#pragma unroll
    for (int j = 0; j < RS; ++j) s_lrawh[j][h] = __float2half(0.f);
    s_scores[tid] = 0.f; s_scores[256 + tid] = 0.f;
    s_v[h] = vv_g[h];
    s_inx[h] = 0.f;
    if (tid < RS) { s_mask[tid] = -1e30f; s_buck[tid] = 0.f; }
    if (tid == 0) { s_fill = 0; s_upd = 0; s_pos = 0; s_minv = 0.f; s_minp = 0; }
    if (tid < 32) ((float4*)(s_inx + NH))[tid] = ((const float4*)(x + b * NI))[tid];
    const float bfv = bf_g[h], biv = bi_g[h], bov = bo_g[h], bgv = bg_g[h];
    float ct = 0.f;
    int base = 0;
    __syncthreads();

    for (int t = 0; t < T_STEPS; ++t) {
        const int par = t & 1;
        if (t > 0) {
            // ---- A: Va@st & Ua@h_{t-1} partials over this block's k-slice; stage x_t ----
            float pq = 0.f, pu = 0.f;
            {
                const float* stp = s_inx + (r << 6);
                const float* hdp = s_hid + (r << 6);
#pragma unroll
                for (int j = 0; j < 8; ++j) {
                    float4 sa = *(const float4*)(stp + 8 * j);
                    float4 sb = *(const float4*)(stp + 8 * j + 4);
                    uint4 wv = VaW[j];
                    float2 w0 = h2f(wv.x), w1 = h2f(wv.y), w2 = h2f(wv.z), w3 = h2f(wv.w);
                    pq += w0.x * sa.x + w0.y * sa.y + w1.x * sa.z + w1.y * sa.w
                        + w2.x * sb.x + w2.y * sb.y + w3.x * sb.z + w3.y * sb.w;
                    float4 ha = *(const float4*)(hdp + 8 * j);
                    float4 hb = *(const float4*)(hdp + 8 * j + 4);
                    uint4 uv = UaW[j];
                    float2 u0 = h2f(uv.x), u1 = h2f(uv.y), u2 = h2f(uv.z), u3 = h2f(uv.w);
                    pu += u0.x * ha.x + u0.y * ha.y + u1.x * ha.z + u1.y * ha.w
                        + u2.x * hb.x + u2.y * hb.y + u3.x * hb.z + u3.y * hb.w;
                }
                float* s1w = S1 + (((b * 2 + par) * 4 + r) << 9);
                s1w[h] = pq; s1w[256 + h] = pu;
                if (tid < 32)
                    ((float4*)(s_inx + NH))[tid] = ((const float4*)(x + ((size_t)t * NB + b) * NI))[tid];
            }
            group_sync(FLG + ((b * 2 + par) * 2 + 0) * 4, r, t, tid);
            // ---- combine q and Ua@h_{t-1} (fixed r order, bit-identical everywhere) ----
            {
                const float* s1b = S1 + ((b * 2 + par) * 4 << 9);
                float q = 0.f, ua = 0.f;
#pragma unroll
                for (int rr = 0; rr < 4; ++rr) {
                    q  += (rr == r) ? pq : s1b[(rr << 9) + h];
                    ua += (rr == r) ? pu : s1b[(rr << 9) + 256 + h];
                }
                s_q[h] = q;
                s_memua[(base + LK - 1) & (LK - 1)][h] = ua;
            }
            __syncthreads();
            // ---- B: attention scores, 48 rows x 16 lanes, 3 passes ----
            {
                const int l = tid & 15, rbase = tid >> 4;
#pragma unroll
                for (int pass = 0; pass < 3; ++pass) {
                    int row = pass * 16 + rbase;
                    bool isShort = row < LK;
                    bool skip = isShort ? (row < LK - t) : (s_mask[row - LK] < -1e29f);
                    float esv = -1e30f;
                    if (!skip) {
                        float p = 0.f;
                        if (isShort) {
                            const float* ua = s_memua[(base + row) & (LK - 1)];
#pragma unroll
                            for (int j = 0; j < 16; ++j) {
                                int hh = l + (j << 4);
                                p += s_v[hh] * ftanh(s_q[hh] + ua[hh]);
                            }
                        } else {
                            const __half* ua = LUAH + (row - LK) * NH;
#pragma unroll
                            for (int j = 0; j < 16; ++j) {
                                int hh = l + (j << 4);
                                p += s_v[hh] * ftanh(s_q[hh] + (float)ua[hh]);
                            }
                        }
                        p += __shfl_xor(p, 1, 16);
                        p += __shfl_xor(p, 2, 16);
                        p += __shfl_xor(p, 4, 16);
                        p += __shfl_xor(p, 8, 16);
                        esv = p;
                    }
                    if (l == 0) s_es[row] = esv;
                }
            }
            __syncthreads();
            // ---- C: softmax (wave 0) + bucket argmin (wave 1) ----
            if (tid < 64) {
                float e = (tid < NS) ? s_es[tid] : -1e30f;
                float m = e;
                for (int off = 32; off; off >>= 1) m = fmaxf(m, __shfl_xor(m, off));
                float a = (tid < NS) ? __expf(e - m) : 0.f;
                float ssum = a;
                for (int off = 32; off; off >>= 1) ssum += __shfl_xor(ssum, off);
                if (tid < NS) s_al[tid] = a * __builtin_amdgcn_rcpf(ssum);
            } else if (tid < 96) {
                int l = tid - 64;
                float v = s_buck[l]; int idx = l;
#pragma unroll
                for (int off = 1; off < 32; off <<= 1) {
                    float v2 = __shfl_xor(v, off, 32);
                    int  i2 = __shfl_xor(idx, off, 32);
                    if (v2 < v || (v2 == v && i2 < idx)) { v = v2; idx = i2; }
                }
                if (l == 0) { s_minv = v; s_minp = idx; }
            }
            __syncthreads();
            // ---- D: ct_att + st; detached score accum; bucket decision ----
            {
                float catt = 0.f;
#pragma unroll
                for (int n = 0; n < LK; ++n) catt += s_al[n] * s_mem[(base + n) & (LK - 1)][h];
#pragma unroll
                for (int n = 0; n < RS; ++n) catt += s_al[LK + n] * (float)s_lrawh[n][h];
                float stn = 0.5f * (s_mem[(base + LK - 1) & (LK - 1)][h] + catt);
                if (tid >= 1 && tid < LK) {
                    int time = t - LK + tid;
                    if (time >= 0) s_scores[time] += s_al[tid];
                } else if (tid == LK) {   // owns slot t-LK: accumulate + decide atomically (single thread)
                    int upd = 0, pos = 0;
                    if (t >= LK) {
                        float cs = s_scores[t - LK] + s_al[0];
                        s_scores[t - LK] = cs;
                        int fill = s_fill;
                        bool full = fill >= RS;
                        upd = (!full) || (cs > s_minv);
                        pos = full ? s_minp : fill;
                        if (upd) { s_mask[pos] = 0.f; s_buck[pos] = cs; if (!full) s_fill = fill + 1; }
                    }
                    s_upd = upd; s_pos = pos;
                }
                s_inx[h] = stn;
            }
            __syncthreads();
        }
        // ---- F: gate partials over [st|x] k-slice; eviction of oldest ring slot ----
        float4 acc = make_float4(0.f, 0.f, 0.f, 0.f);
        {
            const float* sp = s_inx + r * 96;
#pragma unroll
            for (int j = 0; j < 48; ++j) {
                float2 sv = *(const float2*)(sp + 2 * j);
                uint4 w = GW[j];
                float2 wf = h2f(w.x), wi = h2f(w.y), wo = h2f(w.z), wg = h2f(w.w);
                acc.x += wf.x * sv.x + wf.y * sv.y;
                acc.y += wi.x * sv.x + wi.y * sv.y;
                acc.z += wo.x * sv.x + wo.y * sv.y;
                acc.w += wg.x * sv.x + wg.y * sv.y;
            }
            S2[(((b * 2 + par) * 4 + r) << 8) + h] = acc;
            if (s_upd) {
                int p0 = base & (LK - 1), pos = s_pos;
                s_lrawh[pos][h] = __float2half(s_mem[p0][h]);
                if (r == 0) LUAH[pos * NH + h] = __float2half(s_memua[p0][h]);
            }
        }
        group_sync(FLG + ((b * 2 + par) * 2 + 1) * 4, r, t, tid);
        // ---- G: combine gates + activations + state update + ring push ----
        {
            const float4* s2b = S2 + ((b * 2 + par) * 4 << 8);
            float pf = 0.f, pi = 0.f, po = 0.f, pg = 0.f;
#pragma unroll
            for (int rr = 0; rr < 4; ++rr) {
                float4 g = (rr == r) ? acc : s2b[(rr << 8) + h];
                pf += g.x; pi += g.y; po += g.z; pg += g.w;
            }
            float f  = fsig(pf + bfv);
            float ii = fsig(pi + biv);
            float o  = fsig(po + bov);
            float g  = ftanh(pg + bgv);
            ct = f * ct + ii * g;
            float hid = o * ftanh(ct);
            s_hid[h] = hid;
            if (r == 0) out[((size_t)t * NB + b) * NH + h] = hid;
            s_mem[base & (LK - 1)][h] = hid;
        }
        base++;
        __syncthreads();
    }
}

extern "C" void kernel_launch(void* const* d_in, const int* in_sizes, int n_in,
                              void* d_out, int out_size, void* d_ws, size_t ws_size,
                              hipStream_t stream) {
    const float* x  = (const float*)d_in[0];
    const float* Wf = (const float*)d_in[1];
    const float* bf = (const float*)d_in[2];
    const float* Wi = (const float*)d_in[3];
    const float* bi = (const float*)d_in[4];
    const float* Wo = (const float*)d_in[5];
    const float* bo = (const float*)d_in[6];
    const float* Wg = (const float*)d_in[7];
    const float* bg = (const float*)d_in[8];
    const float* Ua = (const float*)d_in[9];
    const float* Va = (const float*)d_in[10];
    const float* vv = (const float*)d_in[11];
    unsigned char* ws = (unsigned char*)d_ws;
    float* out = (float*)d_out;

    prep_weights<<<256, 256, 0, stream>>>(Wf, Wi, Wo, Wg, Ua, Va, ws);
    rel_lstm4<<<256, 256, 0, stream>>>(x, bf, bi, bo, bg, vv, ws, out);
}

// Round 5
// 18799.104 us; speedup vs baseline: 1.6182x; 1.6182x over previous
//
#include <hip/hip_runtime.h>
#include <hip/hip_fp16.h>

#define T_STEPS 512
#define NB      64
#define NI      128
#define NH      256
#define LK      16
#define RS      32
#define NS      (LK + RS)

// ws layout (bytes)
#define WP_OFF    0           // uint4[192*256]: gate weights, k-pair packed 4x half2 (f,i,o,g)
#define VAP8_OFF  786432      // uint4[32*256]: Va^T, 8 consecutive k per entry
#define UAP8_OFF  917504      // uint4[32*256]: Ua^T
#define LUAH_OFF  1048576     // half[64][32][256]: Ua@long_mem cache (1 MB)

typedef _Float16 hh2 __attribute__((ext_vector_type(2)));
union H2U { unsigned int u; hh2 h; };
__device__ __forceinline__ hh2 as_h2(unsigned int u) { H2U c; c.u = u; return c.h; }
__device__ __forceinline__ float fdot2(unsigned int a, hh2 b, float c) {
    return __builtin_amdgcn_fdot2(as_h2(a), b, c, false);
}

__device__ __forceinline__ float fsig(float x) {
    return __builtin_amdgcn_rcpf(1.0f + __expf(-x));
}
__device__ __forceinline__ float ftanh(float x) {
    x = fminf(15.0f, fmaxf(-15.0f, x));
    float e = __expf(2.0f * x);
    return (e - 1.0f) * __builtin_amdgcn_rcpf(e + 1.0f);
}

__global__ void prep_weights(const float* __restrict__ Wf, const float* __restrict__ Wi,
                             const float* __restrict__ Wo, const float* __restrict__ Wg,
                             const float* __restrict__ Ua, const float* __restrict__ Va,
                             unsigned char* __restrict__ ws) {
    int e = blockIdx.x * 256 + threadIdx.x;   // 0..65535
    if (e < 49152) {                          // WP: e = k2*256 + h
        int h = e & 255, k2 = e >> 8, k = 2 * k2;
        uint4 w; __half2 t;
        t = __floats2half2_rn(Wf[h * 384 + k], Wf[h * 384 + k + 1]); w.x = *(unsigned int*)&t;
        t = __floats2half2_rn(Wi[h * 384 + k], Wi[h * 384 + k + 1]); w.y = *(unsigned int*)&t;
        t = __floats2half2_rn(Wo[h * 384 + k], Wo[h * 384 + k + 1]); w.z = *(unsigned int*)&t;
        t = __floats2half2_rn(Wg[h * 384 + k], Wg[h * 384 + k + 1]); w.w = *(unsigned int*)&t;
        ((uint4*)(ws + WP_OFF))[e] = w;
    } else {                                  // Va/Ua 8-k packs
        int e2 = e - 49152;                   // 0..16383
        const float* S = (e2 < 8192) ? Va : Ua;
        int e3 = e2 & 8191;
        int h = e3 & 255, j = e3 >> 8, k = 8 * j;
        uint4 w; __half2 t;
        t = __floats2half2_rn(S[h * 256 + k + 0], S[h * 256 + k + 1]); w.x = *(unsigned int*)&t;
        t = __floats2half2_rn(S[h * 256 + k + 2], S[h * 256 + k + 3]); w.y = *(unsigned int*)&t;
        t = __floats2half2_rn(S[h * 256 + k + 4], S[h * 256 + k + 5]); w.z = *(unsigned int*)&t;
        t = __floats2half2_rn(S[h * 256 + k + 6], S[h * 256 + k + 7]); w.w = *(unsigned int*)&t;
        ((uint4*)(ws + VAP8_OFF))[e2] = w;    // VaP8 then UaP8 contiguous
    }
}

// One block (1024 threads, 16 waves) per sample. Weights live in VGPR+AGPR.
__global__ __launch_bounds__(1024, 1) void rel_lstm(
    const float* __restrict__ x,
    const float* __restrict__ bf_g, const float* __restrict__ bi_g,
    const float* __restrict__ bo_g, const float* __restrict__ bg_g,
    const float* __restrict__ vv_g,
    unsigned char* __restrict__ ws, float* __restrict__ out)
{
    const int tid  = threadIdx.x;
    const int b    = blockIdx.x;
    const int role = tid >> 8;     // 0..3 (k-slice)
    const int h    = tid & 255;

    const uint4* __restrict__ WPp = (const uint4*)(ws + WP_OFF);
    const uint4* __restrict__ VAp = (const uint4*)(ws + VAP8_OFF);
    const uint4* __restrict__ UAp = (const uint4*)(ws + UAP8_OFF);
    __half* __restrict__ LUAH = (__half*)(ws + LUAH_OFF) + b * (RS * NH);

    // ---- persistent weights: 256 regs/thread (arch VGPR + AGPR unified file) ----
    uint4 GW[48];          // gates, k2 in [48*role, 48*role+48) over [st|x]
    uint4 VaW[8], UaW[8];  // Va^T / Ua^T, k in [64*role, 64*role+64)
#pragma unroll
    for (int j = 0; j < 48; ++j) GW[j] = WPp[(role * 48 + j) * NH + h];
#pragma unroll
    for (int j = 0; j < 8; ++j) { VaW[j] = VAp[(role * 8 + j) * NH + h]; UaW[j] = UAp[(role * 8 + j) * NH + h]; }

    __shared__ __align__(16) __half s_inx[NH + NI];   // [st | x] as half2-packed
    __shared__ __align__(16) __half s_mem[LK][NH];    // hidden ring (half)
    __shared__ float s_hid[NH];                       // h_{t-1} fp32 (for exact st formula)
    __shared__ __half s_memua[LK][NH + 4];            // cached Ua@h ring (half)
    __shared__ __half s_lrawh[RS][NH];                // long raw memory (half)
    __shared__ float s_q[NH], s_v[NH];
    __shared__ __align__(16) float s_scr[3072];       // partial-combine scratch
    __shared__ float s_es[NS], s_al[NS];
    __shared__ float s_scores[T_STEPS];
    __shared__ float s_mask[RS], s_buck[RS];
    __shared__ float s_minv;
    __shared__ int s_minp, s_fill, s_upd, s_pos;

    // ---- init ----
    {
        __half z = __float2half(0.f);
#pragma unroll
        for (int j = 0; j < 4; ++j) s_mem[(tid >> 8) * 4 + j][h] = z;
#pragma unroll
        for (int j = 0; j < 4; ++j) s_memua[(tid >> 8) * 4 + j][h] = z;
#pragma unroll
        for (int j = 0; j < 8; ++j) s_lrawh[(tid >> 7) * 4 + (j >> 1)][((tid & 127) << 1) | (j & 1)] = z;
        if (tid < 512) s_scores[tid] = 0.f;
        if (tid < NH) { s_v[tid] = vv_g[tid]; s_inx[tid] = z; s_hid[tid] = 0.f; }
        if (tid < RS) { s_mask[tid] = -1e30f; s_buck[tid] = 0.f; }
        if (tid == 0) { s_fill = 0; s_upd = 0; s_pos = 0; s_minv = 0.f; s_minp = 0; }
        if (tid >= 960) {   // stage x_0 as half2
            int l = tid - 960;
            float2 xv = ((const float2*)(x + b * NI))[l];
            __half2 hv = __floats2half2_rn(xv.x, xv.y);
            *(unsigned int*)&s_inx[NH + 2 * l] = *(unsigned int*)&hv;
        }
    }
    const float bfv = bf_g[h], biv = bi_g[h], bov = bo_g[h], bgv = bg_g[h];
    float ct = 0.f;
    int base = 0;
    __syncthreads();

    for (int t = 0; t < T_STEPS; ++t) {
        if (t > 0) {
            // ---- P1: q & ua partials over this role's 64-k slice (dot2) ; stage x_t ----
            {
                const unsigned int* in2 = (const unsigned int*)s_inx;                      // st half2
                const unsigned int* hm2 = (const unsigned int*)&s_mem[(base + LK - 1) & (LK - 1)][0]; // h_{t-1}
                float pq = 0.f, pu = 0.f;
#pragma unroll
                for (int j = 0; j < 8; ++j) {
                    int k0 = role * 32 + 4 * j;     // half2 index
                    uint4 wv = VaW[j], uv = UaW[j];
                    hh2 s0 = as_h2(in2[k0]), s1 = as_h2(in2[k0 + 1]), s2 = as_h2(in2[k0 + 2]), s3 = as_h2(in2[k0 + 3]);
                    pq = fdot2(wv.x, s0, pq); pq = fdot2(wv.y, s1, pq);
                    pq = fdot2(wv.z, s2, pq); pq = fdot2(wv.w, s3, pq);
                    hh2 h0 = as_h2(hm2[k0]), h1 = as_h2(hm2[k0 + 1]), h2v = as_h2(hm2[k0 + 2]), h3 = as_h2(hm2[k0 + 3]);
                    pu = fdot2(uv.x, h0, pu); pu = fdot2(uv.y, h1, pu);
                    pu = fdot2(uv.z, h2v, pu); pu = fdot2(uv.w, h3, pu);
                }
                s_scr[role * 256 + h] = pq;
                s_scr[1024 + role * 256 + h] = pu;
                if (tid >= 960) {
                    int l = tid - 960;
                    float2 xv = ((const float2*)(x + ((size_t)t * NB + b) * NI))[l];
                    __half2 hv = __floats2half2_rn(xv.x, xv.y);
                    *(unsigned int*)&s_inx[NH + 2 * l] = *(unsigned int*)&hv;
                }
            }
            __syncthreads();
            // ---- P2: combine q; write Ua@h_{t-1} into newest ring slot; bucket argmin ----
            if (tid < 256) {
                s_q[h] = s_scr[h] + s_scr[256 + h] + s_scr[512 + h] + s_scr[768 + h];
            } else if (tid < 512) {
                float ua = s_scr[1024 + h] + s_scr[1280 + h] + s_scr[1536 + h] + s_scr[1792 + h];
                s_memua[(base + LK - 1) & (LK - 1)][h] = __float2half(ua);
            } else if (tid < 544) {
                int l = tid - 512;
                float v = s_buck[l]; int idx = l;
#pragma unroll
                for (int off = 1; off < 32; off <<= 1) {
                    float v2 = __shfl_xor(v, off, 32);
                    int  i2 = __shfl_xor(idx, off, 32);
                    if (v2 < v || (v2 == v && i2 < idx)) { v = v2; idx = i2; }
                }
                if (l == 0) { s_minv = v; s_minp = idx; }
            }
            __syncthreads();
            // ---- P3: attention scores (48 rows x 16 lanes) ----
            if (tid < 768) {
                int row = ((tid >> 6) << 2) + ((tid >> 4) & 3);
                int l = tid & 15;
                bool isShort = row < LK;
                bool skip = isShort ? (row < LK - t) : (s_mask[row - LK] < -1e29f);
                float esv = -1e30f;
                if (!skip) {
                    float p = 0.f;
                    if (isShort) {
                        const __half* ua = s_memua[(base + row) & (LK - 1)];
#pragma unroll
                        for (int j = 0; j < 16; ++j) {
                            int hh = l + (j << 4);
                            p += s_v[hh] * ftanh(s_q[hh] + (float)ua[hh]);
                        }
                    } else {
                        const __half* ua = LUAH + (row - LK) * NH;
#pragma unroll
                        for (int j = 0; j < 16; ++j) {
                            int hh = l + (j << 4);
                            p += s_v[hh] * ftanh(s_q[hh] + (float)ua[hh]);
                        }
                    }
                    p += __shfl_xor(p, 1, 16);
                    p += __shfl_xor(p, 2, 16);
                    p += __shfl_xor(p, 4, 16);
                    p += __shfl_xor(p, 8, 16);
                    esv = p;
                }
                if (l == 0) s_es[row] = esv;
            }
            __syncthreads();
            // ---- P4: softmax over 48 (wave 0) ----
            if (tid < 64) {
                float e = (tid < NS) ? s_es[tid] : -1e30f;
                float m = e;
                for (int off = 32; off; off >>= 1) m = fmaxf(m, __shfl_xor(m, off));
                float a = (tid < NS) ? __expf(e - m) : 0.f;
                float ssum = a;
                for (int off = 32; off; off >>= 1) ssum += __shfl_xor(ssum, off);
                if (tid < NS) s_al[tid] = a * __builtin_amdgcn_rcpf(ssum);
            }
            __syncthreads();
            // ---- P5: ct_att partials (12 slots/role); score accum; bucket decision ----
            {
                float catt = 0.f;
                int n0 = role * 12;
#pragma unroll
                for (int n = n0; n < n0 + 12; ++n) {
                    float a = s_al[n];
                    if (n < LK) catt += a * (float)s_mem[(base + n) & (LK - 1)][h];
                    else        catt += a * (float)s_lrawh[n - LK][h];
                }
                s_scr[role * 256 + h] = catt;
                if (tid >= 1 && tid < LK) {
                    int time = t - LK + tid;
                    if (time >= 0) s_scores[time] += s_al[tid];
                } else if (tid == LK) {
                    int upd = 0, pos = 0;
                    if (t >= LK) {
                        float cs = s_scores[t - LK] + s_al[0];
                        s_scores[t - LK] = cs;
                        int fill = s_fill;
                        bool full = fill >= RS;
                        upd = (!full) || (cs > s_minv);
                        pos = full ? s_minp : fill;
                        if (upd) { s_mask[pos] = 0.f; s_buck[pos] = cs; if (!full) s_fill = fill + 1; }
                    }
                    s_upd = upd; s_pos = pos;
                }
            }
            __syncthreads();
            // ---- P6: st combine -> s_inx (half); eviction of oldest ring slot ----
            {
                int p0 = base & (LK - 1);
                if (tid < 256) {
                    float catt = s_scr[h] + s_scr[256 + h] + s_scr[512 + h] + s_scr[768 + h];
                    float stn = 0.5f * (s_hid[h] + catt);
                    s_inx[h] = __float2half(stn);
                } else if (tid < 512) {
                    if (s_upd) s_lrawh[s_pos][h] = s_mem[p0][h];
                } else if (tid < 768) {
                    if (s_upd) LUAH[s_pos * NH + h] = s_memua[p0][h];
                }
            }
            __syncthreads();
        }
        // ---- P7: gate partials over [st|x] k-slice (dot2, register weights) ----
        float4 acc = make_float4(0.f, 0.f, 0.f, 0.f);
        {
            const unsigned int* st2 = (const unsigned int*)s_inx;   // half2 per k-pair
#pragma unroll
            for (int j = 0; j < 48; ++j) {
                hh2 s = as_h2(st2[role * 48 + j]);
                uint4 w = GW[j];
                acc.x = fdot2(w.x, s, acc.x);
                acc.y = fdot2(w.y, s, acc.y);
                acc.z = fdot2(w.z, s, acc.z);
                acc.w = fdot2(w.w, s, acc.w);
            }
            if (role > 0) ((float4*)s_scr)[(role - 1) * 256 + h] = acc;
        }
        __syncthreads();
        // ---- P8: combine gates + activations + state update + ring push ----
        if (tid < 256) {
            const float4* s4 = (const float4*)s_scr;
            float4 B4 = s4[h], C4 = s4[256 + h], D4 = s4[512 + h];
            float f  = fsig(acc.x + B4.x + C4.x + D4.x + bfv);
            float ii = fsig(acc.y + B4.y + C4.y + D4.y + biv);
            float o  = fsig(acc.z + B4.z + C4.z + D4.z + bov);
            float g  = ftanh(acc.w + B4.w + C4.w + D4.w + bgv);
            ct = f * ct + ii * g;
            float hid = o * ftanh(ct);
            out[((size_t)t * NB + b) * NH + h] = hid;
            s_hid[h] = hid;
            s_mem[base & (LK - 1)][h] = __float2half(hid);
        }
        base++;
        __syncthreads();
    }
}

extern "C" void kernel_launch(void* const* d_in, const int* in_sizes, int n_in,
                              void* d_out, int out_size, void* d_ws, size_t ws_size,
                              hipStream_t stream) {
    const float* x  = (const float*)d_in[0];
    const float* Wf = (const float*)d_in[1];
    const float* bf = (const float*)d_in[2];
    const float* Wi = (const float*)d_in[3];
    const float* bi = (const float*)d_in[4];
    const float* Wo = (const float*)d_in[5];
    const float* bo = (const float*)d_in[6];
    const float* Wg = (const float*)d_in[7];
    const float* bg = (const float*)d_in[8];
    const float* Ua = (const float*)d_in[9];
    const float* Va = (const float*)d_in[10];
    const float* vv = (const float*)d_in[11];
    unsigned char* ws = (unsigned char*)d_ws;
    float* out = (float*)d_out;

    prep_weights<<<256, 256, 0, stream>>>(Wf, Wi, Wo, Wg, Ua, Va, ws);
    rel_lstm<<<NB, 1024, 0, stream>>>(x, bf, bi, bo, bg, vv, ws, out);
}

// Round 6
// 10233.382 us; speedup vs baseline: 2.9727x; 1.8370x over previous
//
#include <hip/hip_runtime.h>
#include <hip/hip_fp16.h>

#define T_STEPS 512
#define NB      64
#define NI      128
#define NH      256
#define LK      16
#define RS      32
#define NS      (LK + RS)

// ws layout (bytes)
#define WP_OFF    0           // uint4[192*256]: gate weights, k-pair packed 4x half2 (f,i,o,g); k2<128 = st part, 128..191 = x part
#define VAP8_OFF  786432      // uint4[32*256]: Va^T, 8 consecutive k per entry
#define UAP8_OFF  917504      // uint4[32*256]: Ua^T
#define GX_OFF    1048576     // uint2[512*64*256]: fp16 x-part of gate preactivations (f,i | o,g)
// total = 1 MB + 64 MB

typedef _Float16 hh2 __attribute__((ext_vector_type(2)));
union H2U { unsigned int u; hh2 h; };
__device__ __forceinline__ hh2 as_h2(unsigned int u) { H2U c; c.u = u; return c.h; }
__device__ __forceinline__ float fdot2(unsigned int a, hh2 b, float c) {
    return __builtin_amdgcn_fdot2(as_h2(a), b, c, false);
}
__device__ __forceinline__ float2 h2f(unsigned int u) {
    return __half22float2(*(const __half2*)&u);
}
__device__ __forceinline__ float fsig(float x) {
    return __builtin_amdgcn_rcpf(1.0f + __expf(-x));
}
__device__ __forceinline__ float ftanh(float x) {
    x = fminf(15.0f, fmaxf(-15.0f, x));
    float e = __expf(2.0f * x);
    return (e - 1.0f) * __builtin_amdgcn_rcpf(e + 1.0f);
}

__global__ void prep_weights(const float* __restrict__ Wf, const float* __restrict__ Wi,
                             const float* __restrict__ Wo, const float* __restrict__ Wg,
                             const float* __restrict__ Ua, const float* __restrict__ Va,
                             unsigned char* __restrict__ ws) {
    int e = blockIdx.x * 256 + threadIdx.x;   // 0..65535
    if (e < 49152) {                          // WP: e = k2*256 + h
        int h = e & 255, k2 = e >> 8, k = 2 * k2;
        uint4 w; __half2 t;
        t = __floats2half2_rn(Wf[h * 384 + k], Wf[h * 384 + k + 1]); w.x = *(unsigned int*)&t;
        t = __floats2half2_rn(Wi[h * 384 + k], Wi[h * 384 + k + 1]); w.y = *(unsigned int*)&t;
        t = __floats2half2_rn(Wo[h * 384 + k], Wo[h * 384 + k + 1]); w.z = *(unsigned int*)&t;
        t = __floats2half2_rn(Wg[h * 384 + k], Wg[h * 384 + k + 1]); w.w = *(unsigned int*)&t;
        ((uint4*)(ws + WP_OFF))[e] = w;
    } else {                                  // Va/Ua 8-k packs
        int e2 = e - 49152;                   // 0..16383
        const float* S = (e2 < 8192) ? Va : Ua;
        int e3 = e2 & 8191;
        int h = e3 & 255, j = e3 >> 8, k = 8 * j;
        uint4 w; __half2 t;
        t = __floats2half2_rn(S[h * 256 + k + 0], S[h * 256 + k + 1]); w.x = *(unsigned int*)&t;
        t = __floats2half2_rn(S[h * 256 + k + 2], S[h * 256 + k + 3]); w.y = *(unsigned int*)&t;
        t = __floats2half2_rn(S[h * 256 + k + 4], S[h * 256 + k + 5]); w.z = *(unsigned int*)&t;
        t = __floats2half2_rn(S[h * 256 + k + 6], S[h * 256 + k + 7]); w.w = *(unsigned int*)&t;
        ((uint4*)(ws + VAP8_OFF))[e2] = w;    // VaP8 then UaP8 contiguous
    }
}

// Parallel GEMM: GX[t][b][h] = fp16(W_x @ x_t) packed (f,i | o,g) as uint2.
__global__ __launch_bounds__(256) void gx_gemm(const float* __restrict__ x,
                                               unsigned char* __restrict__ ws) {
    const int t = blockIdx.x, bg = blockIdx.y, tid = threadIdx.x;
    const uint4* __restrict__ WP = (const uint4*)(ws + WP_OFF);
    uint2* __restrict__ GX = (uint2*)(ws + GX_OFF);
    __shared__ float s_xx[16 * 128];
    const float* xb = x + ((size_t)t * NB + bg * 16) * NI;
#pragma unroll
    for (int r = 0; r < 8; ++r) s_xx[tid + 256 * r] = xb[tid + 256 * r];
    __syncthreads();
    const int h = tid;
    float acc[16][4];
#pragma unroll
    for (int bb = 0; bb < 16; ++bb) { acc[bb][0] = acc[bb][1] = acc[bb][2] = acc[bb][3] = 0.f; }
    for (int k2 = 128; k2 < 192; ++k2) {
        uint4 w = WP[k2 * NH + h];
        float2 wf = h2f(w.x), wi = h2f(w.y), wo = h2f(w.z), wg = h2f(w.w);
        int kk = 2 * k2 - 256;
#pragma unroll
        for (int bb = 0; bb < 16; ++bb) {
            float2 xv = *(const float2*)(s_xx + bb * 128 + kk);
            acc[bb][0] += wf.x * xv.x + wf.y * xv.y;
            acc[bb][1] += wi.x * xv.x + wi.y * xv.y;
            acc[bb][2] += wo.x * xv.x + wo.y * xv.y;
            acc[bb][3] += wg.x * xv.x + wg.y * xv.y;
        }
    }
#pragma unroll
    for (int bb = 0; bb < 16; ++bb) {
        __half2 p0 = __floats2half2_rn(acc[bb][0], acc[bb][1]);
        __half2 p1 = __floats2half2_rn(acc[bb][2], acc[bb][3]);
        uint2 u; u.x = *(unsigned int*)&p0; u.y = *(unsigned int*)&p1;
        GX[((size_t)t * NB + bg * 16 + bb) * NH + h] = u;
    }
}

// One block (1024 threads, 16 waves) per sample. Weights streamed from L2 via dot2.
__global__ __launch_bounds__(1024, 1) void rel_lstm(
    const float* __restrict__ bf_g, const float* __restrict__ bi_g,
    const float* __restrict__ bo_g, const float* __restrict__ bg_g,
    const float* __restrict__ vv_g,
    unsigned char* __restrict__ ws, float* __restrict__ out)
{
    const int tid  = threadIdx.x;
    const int b    = blockIdx.x;
    const int role = tid >> 8;     // 0..3 (k-slice)
    const int h    = tid & 255;

    const uint4* __restrict__ WPp = (const uint4*)(ws + WP_OFF);
    const uint4* __restrict__ VAp = (const uint4*)(ws + VAP8_OFF);
    const uint4* __restrict__ UAp = (const uint4*)(ws + UAP8_OFF);
    const uint2* __restrict__ GXp = (const uint2*)(ws + GX_OFF);

    __shared__ __align__(16) __half s_inx[NH];        // st (half2-packed)
    __shared__ float s_hid[NH];                       // h_{t-1} fp32
    __shared__ __align__(16) __half s_mem[LK][NH];    // hidden ring
    __shared__ __half s_memua[LK][NH + 8];            // Ua@h ring (+8 pad: strided reads)
    __shared__ __half s_lraw[RS][NH];                 // long raw memory
    __shared__ __half s_luah[RS][NH + 8];             // Ua@long cache (+8 pad)
    __shared__ float s_q[NH], s_v[NH];
    __shared__ __align__(16) float s_scr[3072];       // partial-combine scratch
    __shared__ float s_es[NS], s_al[NS];
    __shared__ float s_scores[T_STEPS];
    __shared__ float s_mask[RS], s_buck[RS];
    __shared__ float s_minv;
    __shared__ int s_minp, s_fill, s_upd, s_pos;

    // ---- init ----
    {
        __half z = __float2half(0.f);
#pragma unroll
        for (int j = 0; j < 4; ++j) { s_mem[role * 4 + j][h] = z; s_memua[role * 4 + j][h] = z; }
#pragma unroll
        for (int j = 0; j < 8; ++j) { s_lraw[role * 8 + j][h] = z; s_luah[role * 8 + j][h] = z; }
        if (tid < 512) s_scores[tid] = 0.f;
        if (tid < NH) { s_v[tid] = vv_g[tid]; s_inx[tid] = z; s_hid[tid] = 0.f; }
        if (tid < RS) { s_mask[tid] = -1e30f; s_buck[tid] = 0.f; }
        if (tid == 0) { s_fill = 0; s_upd = 0; s_pos = 0; s_minv = 0.f; s_minp = 0; }
    }
    const float bfv = bf_g[h], biv = bi_g[h], bov = bo_g[h], bgv = bg_g[h];
    float ct = 0.f;
    int base = 0;
    uint2 gx = make_uint2(0u, 0u);
    if (tid < NH) gx = GXp[b * NH + h];     // step-0 x-gates
    __syncthreads();

    for (int t = 0; t < T_STEPS; ++t) {
        if (t > 0) {
            // ---- P1: q = Va@st_{t-1}, ua = Ua@h_{t-1} partials (dot2, streamed); fetch GX_t ----
            {
                const unsigned int* in2 = (const unsigned int*)s_inx;
                const unsigned int* hm2 = (const unsigned int*)&s_mem[(base + LK - 1) & (LK - 1)][0];
                float pq = 0.f, pu = 0.f;
#pragma unroll
                for (int j = 0; j < 8; ++j) {
                    int k0 = role * 32 + 4 * j;
                    uint4 wv = VAp[(role * 8 + j) * NH + h];
                    pq = fdot2(wv.x, as_h2(in2[k0]), pq);
                    pq = fdot2(wv.y, as_h2(in2[k0 + 1]), pq);
                    pq = fdot2(wv.z, as_h2(in2[k0 + 2]), pq);
                    pq = fdot2(wv.w, as_h2(in2[k0 + 3]), pq);
                    uint4 uv = UAp[(role * 8 + j) * NH + h];
                    pu = fdot2(uv.x, as_h2(hm2[k0]), pu);
                    pu = fdot2(uv.y, as_h2(hm2[k0 + 1]), pu);
                    pu = fdot2(uv.z, as_h2(hm2[k0 + 2]), pu);
                    pu = fdot2(uv.w, as_h2(hm2[k0 + 3]), pu);
                }
                s_scr[role * 256 + h] = pq;
                s_scr[1024 + role * 256 + h] = pu;
                if (tid < NH) gx = GXp[((size_t)t * NB + b) * NH + h];
            }
            __syncthreads();
            // ---- P2: combine q; Ua@h_{t-1} -> newest ring slot; bucket argmin ----
            if (tid < 256) {
                s_q[h] = s_scr[h] + s_scr[256 + h] + s_scr[512 + h] + s_scr[768 + h];
            } else if (tid < 512) {
                float ua = s_scr[1024 + h] + s_scr[1280 + h] + s_scr[1536 + h] + s_scr[1792 + h];
                s_memua[(base + LK - 1) & (LK - 1)][h] = __float2half(ua);
            } else if (tid < 544) {
                int l = tid - 512;
                float v = s_buck[l]; int idx = l;
#pragma unroll
                for (int off = 1; off < 32; off <<= 1) {
                    float v2 = __shfl_xor(v, off, 32);
                    int  i2 = __shfl_xor(idx, off, 32);
                    if (v2 < v || (v2 == v && i2 < idx)) { v = v2; idx = i2; }
                }
                if (l == 0) { s_minv = v; s_minp = idx; }
            }
            __syncthreads();
            // ---- P3: attention scores, 48 rows x 16 lanes ----
            if (tid < 768) {
                int row = ((tid >> 6) << 2) + ((tid >> 4) & 3);
                int l = tid & 15;
                bool isShort = row < LK;
                bool skip = isShort ? (row < LK - t) : (s_mask[row - LK] < -1e29f);
                float esv = -1e30f;
                if (!skip) {
                    const __half* ua = isShort ? &s_memua[(base + row) & (LK - 1)][0]
                                               : &s_luah[row - LK][0];
                    float p = 0.f;
#pragma unroll
                    for (int j = 0; j < 16; ++j) {
                        int hh = l + (j << 4);
                        p += s_v[hh] * ftanh(s_q[hh] + (float)ua[hh]);
                    }
                    p += __shfl_xor(p, 1, 16);
                    p += __shfl_xor(p, 2, 16);
                    p += __shfl_xor(p, 4, 16);
                    p += __shfl_xor(p, 8, 16);
                    esv = p;
                }
                if (l == 0) s_es[row] = esv;
            }
            __syncthreads();
            // ---- P4: softmax over 48 (wave 0) ----
            if (tid < 64) {
                float e = (tid < NS) ? s_es[tid] : -1e30f;
                float m = e;
                for (int off = 32; off; off >>= 1) m = fmaxf(m, __shfl_xor(m, off));
                float a = (tid < NS) ? __expf(e - m) : 0.f;
                float ssum = a;
                for (int off = 32; off; off >>= 1) ssum += __shfl_xor(ssum, off);
                if (tid < NS) s_al[tid] = a * __builtin_amdgcn_rcpf(ssum);
            }
            __syncthreads();
            // ---- P5: ct_att partials; detached score accum; bucket decision ----
            {
                float catt = 0.f;
                int n0 = role * 12;
#pragma unroll
                for (int n = n0; n < n0 + 12; ++n) {
                    float a = s_al[n];
                    if (n < LK) catt += a * (float)s_mem[(base + n) & (LK - 1)][h];
                    else        catt += a * (float)s_lraw[n - LK][h];
                }
                s_scr[role * 256 + h] = catt;
                if (tid >= 1 && tid < LK) {
                    int time = t - LK + tid;
                    if (time >= 0) s_scores[time] += s_al[tid];
                } else if (tid == LK) {
                    int upd = 0, pos = 0;
                    if (t >= LK) {
                        float cs = s_scores[t - LK] + s_al[0];
                        s_scores[t - LK] = cs;
                        int fill = s_fill;
                        bool full = fill >= RS;
                        upd = (!full) || (cs > s_minv);
                        pos = full ? s_minp : fill;
                        if (upd) { s_mask[pos] = 0.f; s_buck[pos] = cs; if (!full) s_fill = fill + 1; }
                    }
                    s_upd = upd; s_pos = pos;
                }
            }
            __syncthreads();
            // ---- P6: st combine -> s_inx; evict oldest ring slot into buckets ----
            {
                int p0 = base & (LK - 1);
                if (tid < 256) {
                    float catt = s_scr[h] + s_scr[256 + h] + s_scr[512 + h] + s_scr[768 + h];
                    s_inx[h] = __float2half(0.5f * (s_hid[h] + catt));
                } else if (tid < 512) {
                    if (s_upd) s_lraw[s_pos][h] = s_mem[p0][h];
                } else if (tid < 768) {
                    if (s_upd) s_luah[s_pos][h] = s_memua[p0][h];
                }
            }
            __syncthreads();
        }
        // ---- P7: gate partials over st (128 k2 streamed, dot2, 4-way k-split) ----
        float4 acc = make_float4(0.f, 0.f, 0.f, 0.f);
        {
            const unsigned int* st2 = (const unsigned int*)s_inx;
#pragma unroll
            for (int j = 0; j < 32; ++j) {
                int k2 = role * 32 + j;
                uint4 w = WPp[k2 * NH + h];
                hh2 s = as_h2(st2[k2]);
                acc.x = fdot2(w.x, s, acc.x);
                acc.y = fdot2(w.y, s, acc.y);
                acc.z = fdot2(w.z, s, acc.z);
                acc.w = fdot2(w.w, s, acc.w);
            }
            if (role > 0) ((float4*)s_scr)[(role - 1) * 256 + h] = acc;
        }
        __syncthreads();
        // ---- P8: combine + GX + bias -> activations, state update, ring push ----
        if (tid < 256) {
            const float4* s4 = (const float4*)s_scr;
            float4 B4 = s4[h], C4 = s4[256 + h], D4 = s4[512 + h];
            float2 fi = h2f(gx.x), og = h2f(gx.y);
            float f  = fsig(acc.x + B4.x + C4.x + D4.x + fi.x + bfv);
            float ii = fsig(acc.y + B4.y + C4.y + D4.y + fi.y + biv);
            float o  = fsig(acc.z + B4.z + C4.z + D4.z + og.x + bov);
            float g  = ftanh(acc.w + B4.w + C4.w + D4.w + og.y + bgv);
            ct = f * ct + ii * g;
            float hid = o * ftanh(ct);
            out[((size_t)t * NB + b) * NH + h] = hid;
            s_hid[h] = hid;
            s_mem[base & (LK - 1)][h] = __float2half(hid);
        }
        base++;
        __syncthreads();
    }
}

extern "C" void kernel_launch(void* const* d_in, const int* in_sizes, int n_in,
                              void* d_out, int out_size, void* d_ws, size_t ws_size,
                              hipStream_t stream) {
    const float* x  = (const float*)d_in[0];
    const float* Wf = (const float*)d_in[1];
    const float* bf = (const float*)d_in[2];
    const float* Wi = (const float*)d_in[3];
    const float* bi = (const float*)d_in[4];
    const float* Wo = (const float*)d_in[5];
    const float* bo = (const float*)d_in[6];
    const float* Wg = (const float*)d_in[7];
    const float* bg = (const float*)d_in[8];
    const float* Ua = (const float*)d_in[9];
    const float* Va = (const float*)d_in[10];
    const float* vv = (const float*)d_in[11];
    unsigned char* ws = (unsigned char*)d_ws;
    float* out = (float*)d_out;

    prep_weights<<<256, 256, 0, stream>>>(Wf, Wi, Wo, Wg, Ua, Va, ws);
    gx_gemm<<<dim3(T_STEPS, 4), 256, 0, stream>>>(x, ws);
    rel_lstm<<<NB, 1024, 0, stream>>>(bf, bi, bo, bg, vv, ws, out);
}

// Round 7
// 10033.618 us; speedup vs baseline: 3.0318x; 1.0199x over previous
//
#include <hip/hip_runtime.h>
#include <hip/hip_fp16.h>

#define T_STEPS 512
#define NB      64
#define NI      128
#define NH      256
#define LK      16
#define RS      32
#define NS      (LK + RS)

// ws layout (bytes)
#define WP_OFF    0           // uint4[192*256]: gate weights, k-pair packed 4x half2 (f,i,o,g); k2<128 = st part, 128..191 = x part
#define VAP8_OFF  786432      // uint4[32*256]: Va^T, 8 consecutive k per entry
#define UAP8_OFF  917504      // uint4[32*256]: Ua^T
#define GX_OFF    1048576     // uint2[512*64*256]: fp16 x-part of gate preactivations (f,i | o,g)

typedef _Float16 hh2 __attribute__((ext_vector_type(2)));
union H2U { unsigned int u; hh2 h; };
__device__ __forceinline__ hh2 as_h2(unsigned int u) { H2U c; c.u = u; return c.h; }
__device__ __forceinline__ float fdot2(unsigned int a, hh2 b, float c) {
    return __builtin_amdgcn_fdot2(as_h2(a), b, c, false);
}
__device__ __forceinline__ float2 h2f(unsigned int u) {
    return __half22float2(*(const __half2*)&u);
}
__device__ __forceinline__ float fsig(float x) {
    return __builtin_amdgcn_rcpf(1.0f + __expf(-x));
}
__device__ __forceinline__ float ftanh(float x) {
    x = fminf(15.0f, fmaxf(-15.0f, x));
    float e = __expf(2.0f * x);
    return (e - 1.0f) * __builtin_amdgcn_rcpf(e + 1.0f);
}

__global__ void prep_weights(const float* __restrict__ Wf, const float* __restrict__ Wi,
                             const float* __restrict__ Wo, const float* __restrict__ Wg,
                             const float* __restrict__ Ua, const float* __restrict__ Va,
                             unsigned char* __restrict__ ws) {
    int e = blockIdx.x * 256 + threadIdx.x;   // 0..65535
    if (e < 49152) {
        int h = e & 255, k2 = e >> 8, k = 2 * k2;
        uint4 w; __half2 t;
        t = __floats2half2_rn(Wf[h * 384 + k], Wf[h * 384 + k + 1]); w.x = *(unsigned int*)&t;
        t = __floats2half2_rn(Wi[h * 384 + k], Wi[h * 384 + k + 1]); w.y = *(unsigned int*)&t;
        t = __floats2half2_rn(Wo[h * 384 + k], Wo[h * 384 + k + 1]); w.z = *(unsigned int*)&t;
        t = __floats2half2_rn(Wg[h * 384 + k], Wg[h * 384 + k + 1]); w.w = *(unsigned int*)&t;
        ((uint4*)(ws + WP_OFF))[e] = w;
    } else {
        int e2 = e - 49152;
        const float* S = (e2 < 8192) ? Va : Ua;
        int e3 = e2 & 8191;
        int h = e3 & 255, j = e3 >> 8, k = 8 * j;
        uint4 w; __half2 t;
        t = __floats2half2_rn(S[h * 256 + k + 0], S[h * 256 + k + 1]); w.x = *(unsigned int*)&t;
        t = __floats2half2_rn(S[h * 256 + k + 2], S[h * 256 + k + 3]); w.y = *(unsigned int*)&t;
        t = __floats2half2_rn(S[h * 256 + k + 4], S[h * 256 + k + 5]); w.z = *(unsigned int*)&t;
        t = __floats2half2_rn(S[h * 256 + k + 6], S[h * 256 + k + 7]); w.w = *(unsigned int*)&t;
        ((uint4*)(ws + VAP8_OFF))[e2] = w;
    }
}

__global__ __launch_bounds__(256) void gx_gemm(const float* __restrict__ x,
                                               unsigned char* __restrict__ ws) {
    const int t = blockIdx.x, bg = blockIdx.y, tid = threadIdx.x;
    const uint4* __restrict__ WP = (const uint4*)(ws + WP_OFF);
    uint2* __restrict__ GX = (uint2*)(ws + GX_OFF);
    __shared__ float s_xx[16 * 128];
    const float* xb = x + ((size_t)t * NB + bg * 16) * NI;
#pragma unroll
    for (int r = 0; r < 8; ++r) s_xx[tid + 256 * r] = xb[tid + 256 * r];
    __syncthreads();
    const int h = tid;
    float acc[16][4];
#pragma unroll
    for (int bb = 0; bb < 16; ++bb) { acc[bb][0] = acc[bb][1] = acc[bb][2] = acc[bb][3] = 0.f; }
    for (int k2 = 128; k2 < 192; ++k2) {
        uint4 w = WP[k2 * NH + h];
        float2 wf = h2f(w.x), wi = h2f(w.y), wo = h2f(w.z), wg = h2f(w.w);
        int kk = 2 * k2 - 256;
#pragma unroll
        for (int bb = 0; bb < 16; ++bb) {
            float2 xv = *(const float2*)(s_xx + bb * 128 + kk);
            acc[bb][0] += wf.x * xv.x + wf.y * xv.y;
            acc[bb][1] += wi.x * xv.x + wi.y * xv.y;
            acc[bb][2] += wo.x * xv.x + wo.y * xv.y;
            acc[bb][3] += wg.x * xv.x + wg.y * xv.y;
        }
    }
#pragma unroll
    for (int bb = 0; bb < 16; ++bb) {
        __half2 p0 = __floats2half2_rn(acc[bb][0], acc[bb][1]);
        __half2 p1 = __floats2half2_rn(acc[bb][2], acc[bb][3]);
        uint2 u; u.x = *(unsigned int*)&p0; u.y = *(unsigned int*)&p1;
        GX[((size_t)t * NB + bg * 16 + bb) * NH + h] = u;
    }
}

// One block (1024 threads) per sample; 6 barriers/step; rotated, batched weight stream.
__global__ __launch_bounds__(1024, 1) void rel_lstm(
    const float* __restrict__ bf_g, const float* __restrict__ bi_g,
    const float* __restrict__ bo_g, const float* __restrict__ bg_g,
    const float* __restrict__ vv_g,
    unsigned char* __restrict__ ws, float* __restrict__ out)
{
    const int tid  = threadIdx.x;
    const int b    = blockIdx.x;
    const int role = tid >> 8;     // 0..3
    const int h    = tid & 255;

    const uint4* __restrict__ WPp = (const uint4*)(ws + WP_OFF);
    const uint4* __restrict__ VAp = (const uint4*)(ws + VAP8_OFF);
    const uint4* __restrict__ UAp = (const uint4*)(ws + UAP8_OFF);
    const uint2* __restrict__ GXp = (const uint2*)(ws + GX_OFF);

    // per-CU stream decorrelation: blocks on the same XCD (b%8 equal) get distinct offsets
    const int goff = (b >> 3) * 4;   // gate k2 rotation, 0..28
    const int voff = (b >> 3) & 7;   // Va/Ua entry rotation

    __shared__ __align__(16) __half s_inx[NH];        // st_t (half2-packed)
    __shared__ float s_hid[NH];                       // h_{t-1} fp32
    __shared__ __align__(16) __half s_mem[LK][NH];    // hidden ring
    __shared__ __half s_memua[LK][NH + 8];            // Ua@h ring (+8 pad)
    __shared__ __half s_lraw[RS][NH];                 // long raw memory
    __shared__ __half s_luah[RS][NH + 8];             // Ua@long cache (+8 pad)
    __shared__ float s_q[NH], s_v[NH];
    __shared__ __align__(16) float s_scr[4096];       // [0..3071] gate f4 partials; [3072..4095] q/ua partials
    __shared__ float s_es[NS], s_al[NS];
    __shared__ float s_scores[T_STEPS];
    __shared__ float s_mask[RS], s_buck[RS];
    __shared__ float s_minv;
    __shared__ int s_minp, s_fill, s_upd, s_pos;

    // ---- init ----
    {
        __half z = __float2half(0.f);
#pragma unroll
        for (int j = 0; j < 4; ++j) { s_mem[role * 4 + j][h] = z; s_memua[role * 4 + j][h] = z; }
#pragma unroll
        for (int j = 0; j < 8; ++j) { s_lraw[role * 8 + j][h] = z; s_luah[role * 8 + j][h] = z; }
        if (tid < 512) s_scores[tid] = 0.f;
        s_scr[tid] = 0.f; s_scr[1024 + tid] = 0.f; s_scr[2048 + tid] = 0.f; s_scr[3072 + tid] = 0.f;
        if (tid < NH) { s_v[tid] = vv_g[tid]; s_inx[tid] = z; s_hid[tid] = 0.f; s_q[tid] = 0.f; }
        if (tid < RS) { s_mask[tid] = -1e30f; s_buck[tid] = 0.f; }
        if (tid == 0) { s_fill = 0; s_upd = 0; s_pos = 0; s_minv = 0.f; s_minp = 0; }
    }
    const float bfv = bf_g[h], biv = bi_g[h], bov = bo_g[h], bgv = bg_g[h];
    float ct = 0.f;
    int base = 0;
    uint2 gx = make_uint2(0u, 0u);
    if (tid < NH) gx = GXp[b * NH + h];
    __syncthreads();

    for (int t = 0; t < T_STEPS; ++t) {
        float4 acc = make_float4(0.f, 0.f, 0.f, 0.f);
        if (t > 0) {
            // ---- S: scores (48 rows x 16 lanes); argmin (wave 12); ua persist (wave 15) ----
            if (tid < 768) {
                int row = ((tid >> 6) << 2) + ((tid >> 4) & 3);
                int l = tid & 15;
                bool isShort = row < LK;
                bool newest = (row == LK - 1);
                bool skip = isShort ? (row < LK - t) : (s_mask[row - LK] < -1e29f);
                float p = -1e30f;
                if (!skip) {
                    p = 0.f;
                    if (newest) {
#pragma unroll
                        for (int j = 0; j < 16; ++j) {
                            int hh = l + (j << 4);
                            float ua = s_scr[3072 + hh] + s_scr[3328 + hh] + s_scr[3584 + hh] + s_scr[3840 + hh];
                            p += s_v[hh] * ftanh(s_q[hh] + ua);
                        }
                    } else {
                        const __half* ua = isShort ? &s_memua[(base + row) & (LK - 1)][0]
                                                   : &s_luah[row - LK][0];
#pragma unroll
                        for (int j = 0; j < 16; ++j) {
                            int hh = l + (j << 4);
                            p += s_v[hh] * ftanh(s_q[hh] + (float)ua[hh]);
                        }
                    }
                    p += __shfl_xor(p, 1, 16);
                    p += __shfl_xor(p, 2, 16);
                    p += __shfl_xor(p, 4, 16);
                    p += __shfl_xor(p, 8, 16);
                }
                if (l == 0) s_es[row] = p;
            } else if (tid < 800) {
                int l = tid - 768;
                float v = s_buck[l]; int idx = l;
#pragma unroll
                for (int off = 1; off < 32; off <<= 1) {
                    float v2 = __shfl_xor(v, off, 32);
                    int  i2 = __shfl_xor(idx, off, 32);
                    if (v2 < v || (v2 == v && i2 < idx)) { v = v2; idx = i2; }
                }
                if (l == 0) { s_minv = v; s_minp = idx; }
            } else if (tid >= 960) {
                int l = tid - 960;
                int newest = (base + LK - 1) & (LK - 1);
#pragma unroll
                for (int u = 0; u < 4; ++u) {
                    int hh = 4 * l + u;
                    float ua = s_scr[3072 + hh] + s_scr[3328 + hh] + s_scr[3584 + hh] + s_scr[3840 + hh];
                    s_memua[newest][hh] = __float2half(ua);
                }
            }
            __syncthreads();
            // ---- X: softmax over 48 (wave 0) ----
            if (tid < 64) {
                float e = (tid < NS) ? s_es[tid] : -1e30f;
                float m = e;
                for (int off = 32; off; off >>= 1) m = fmaxf(m, __shfl_xor(m, off));
                float a = (tid < NS) ? __expf(e - m) : 0.f;
                float ssum = a;
                for (int off = 32; off; off >>= 1) ssum += __shfl_xor(ssum, off);
                if (tid < NS) s_al[tid] = a * __builtin_amdgcn_rcpf(ssum);
            }
            __syncthreads();
            // ---- C: full ct_att + st (tid<256); score accum + bucket decision (wave 4) ----
            if (tid < 256) {
                float catt = 0.f;
#pragma unroll
                for (int n = 0; n < LK; ++n) catt += s_al[n] * (float)s_mem[(base + n) & (LK - 1)][h];
#pragma unroll
                for (int n = 0; n < RS; ++n) catt += s_al[LK + n] * (float)s_lraw[n][h];
                s_inx[h] = __float2half(0.5f * (s_hid[h] + catt));
            } else if (tid > 256 && tid < 256 + LK) {
                int j = tid - 256;
                int time = t - LK + j;
                if (time >= 0) s_scores[time] += s_al[j];
            } else if (tid == 256) {
                int upd = 0, pos = 0;
                if (t >= LK) {
                    float cs = s_scores[t - LK] + s_al[0];
                    s_scores[t - LK] = cs;
                    int fill = s_fill;
                    bool full = fill >= RS;
                    upd = (!full) || (cs > s_minv);
                    pos = full ? s_minp : fill;
                    if (upd) { s_mask[pos] = 0.f; s_buck[pos] = cs; if (!full) s_fill = fill + 1; }
                }
                s_upd = upd; s_pos = pos;
            }
            __syncthreads();
            // ---- A: gates(st_t) + q_{t+1}=Va@st_t, deep-batched rotated stream ----
            {
                const unsigned int* st2 = (const unsigned int*)s_inx;
                uint4 wb[8], nb[8];
#pragma unroll
                for (int u = 0; u < 8; ++u)
                    wb[u] = WPp[(role * 32 + ((u + goff) & 31)) * NH + h];
#pragma unroll
                for (int jb = 0; jb < 4; ++jb) {
                    if (jb < 3) {
#pragma unroll
                        for (int u = 0; u < 8; ++u)
                            nb[u] = WPp[(role * 32 + ((8 * (jb + 1) + u + goff) & 31)) * NH + h];
                    } else {
#pragma unroll
                        for (int u = 0; u < 8; ++u)
                            nb[u] = VAp[(role * 8 + ((u + voff) & 7)) * NH + h];
                    }
#pragma unroll
                    for (int u = 0; u < 8; ++u) {
                        int k2 = role * 32 + ((8 * jb + u + goff) & 31);
                        hh2 s = as_h2(st2[k2]);
                        acc.x = fdot2(wb[u].x, s, acc.x);
                        acc.y = fdot2(wb[u].y, s, acc.y);
                        acc.z = fdot2(wb[u].z, s, acc.z);
                        acc.w = fdot2(wb[u].w, s, acc.w);
                    }
#pragma unroll
                    for (int u = 0; u < 8; ++u) wb[u] = nb[u];
                }
                float pq = 0.f;
#pragma unroll
                for (int u = 0; u < 8; ++u) {
                    int j = role * 8 + ((u + voff) & 7);
                    pq = fdot2(wb[u].x, as_h2(st2[4 * j + 0]), pq);
                    pq = fdot2(wb[u].y, as_h2(st2[4 * j + 1]), pq);
                    pq = fdot2(wb[u].z, as_h2(st2[4 * j + 2]), pq);
                    pq = fdot2(wb[u].w, as_h2(st2[4 * j + 3]), pq);
                }
                s_scr[3072 + role * 256 + h] = pq;
                if (role > 0) ((float4*)s_scr)[(role - 1) * 256 + h] = acc;
            }
            __syncthreads();
        }
        // ---- F: evict + combine gates + activations + ring push (tid<256); q combine (256-511) ----
        if (tid < 256) {
            int p0 = base & (LK - 1);
            if (s_upd) {
                s_lraw[s_pos][h] = s_mem[p0][h];
                s_luah[s_pos][h] = s_memua[p0][h];
            }
            const float4* s4 = (const float4*)s_scr;
            float4 B4 = s4[h], C4 = s4[256 + h], D4 = s4[512 + h];
            float2 fi = h2f(gx.x), og = h2f(gx.y);
            float f  = fsig(acc.x + B4.x + C4.x + D4.x + fi.x + bfv);
            float ii = fsig(acc.y + B4.y + C4.y + D4.y + fi.y + biv);
            float o  = fsig(acc.z + B4.z + C4.z + D4.z + og.x + bov);
            float g  = ftanh(acc.w + B4.w + C4.w + D4.w + og.y + bgv);
            ct = f * ct + ii * g;
            float hid = o * ftanh(ct);
            out[((size_t)t * NB + b) * NH + h] = hid;
            s_hid[h] = hid;
            s_mem[p0][h] = __float2half(hid);
            if (t + 1 < T_STEPS) gx = GXp[((size_t)(t + 1) * NB + b) * NH + h];
        } else if (tid < 512) {
            s_q[h] = s_scr[3072 + h] + s_scr[3328 + h] + s_scr[3584 + h] + s_scr[3840 + h];
        }
        __syncthreads();
        // ---- B: ua = Ua@h_t partials (rotated); combine folded into next S ----
        {
            const unsigned int* hm2 = (const unsigned int*)&s_mem[base & (LK - 1)][0];
            float pu = 0.f;
            uint4 ub[8];
#pragma unroll
            for (int u = 0; u < 8; ++u)
                ub[u] = UAp[(role * 8 + ((u + voff) & 7)) * NH + h];
#pragma unroll
            for (int u = 0; u < 8; ++u) {
                int j = role * 8 + ((u + voff) & 7);
                pu = fdot2(ub[u].x, as_h2(hm2[4 * j + 0]), pu);
                pu = fdot2(ub[u].y, as_h2(hm2[4 * j + 1]), pu);
                pu = fdot2(ub[u].z, as_h2(hm2[4 * j + 2]), pu);
                pu = fdot2(ub[u].w, as_h2(hm2[4 * j + 3]), pu);
            }
            s_scr[3072 + role * 256 + h] = pu;
        }
        base++;
        __syncthreads();
    }
}

extern "C" void kernel_launch(void* const* d_in, const int* in_sizes, int n_in,
                              void* d_out, int out_size, void* d_ws, size_t ws_size,
                              hipStream_t stream) {
    const float* x  = (const float*)d_in[0];
    const float* Wf = (const float*)d_in[1];
    const float* bf = (const float*)d_in[2];
    const float* Wi = (const float*)d_in[3];
    const float* bi = (const float*)d_in[4];
    const float* Wo = (const float*)d_in[5];
    const float* bo = (const float*)d_in[6];
    const float* Wg = (const float*)d_in[7];
    const float* bg = (const float*)d_in[8];
    const float* Ua = (const float*)d_in[9];
    const float* Va = (const float*)d_in[10];
    const float* vv = (const float*)d_in[11];
    unsigned char* ws = (unsigned char*)d_ws;
    float* out = (float*)d_out;

    prep_weights<<<256, 256, 0, stream>>>(Wf, Wi, Wo, Wg, Ua, Va, ws);
    gx_gemm<<<dim3(T_STEPS, 4), 256, 0, stream>>>(x, ws);
    rel_lstm<<<NB, 1024, 0, stream>>>(bf, bi, bo, bg, vv, ws, out);
}

// Round 8
// 8408.544 us; speedup vs baseline: 3.6178x; 1.1933x over previous
//
#include <hip/hip_runtime.h>
#include <hip/hip_fp16.h>

#define T_STEPS 512
#define NB      64
#define NI      128
#define NH      256
#define LK      16
#define RS      32
#define NS      (LK + RS)

// ws layout (bytes)
#define WP_OFF    0           // uint4[192*256]: gate weights, k-pair packed 4x half2 (f,i,o,g); k2<128 = st part, 128..191 = x part
#define VAP8_OFF  786432      // uint4[32*256]: Va^T, 8 consecutive k per entry
#define UAP8_OFF  917504      // uint4[32*256]: Ua^T
#define GX_OFF    1048576     // uint2[512*64*256]: fp16 x-part of gate preactivations (f,i | o,g)

typedef _Float16 hh2 __attribute__((ext_vector_type(2)));
union H2U { unsigned int u; hh2 h; };
__device__ __forceinline__ hh2 as_h2(unsigned int u) { H2U c; c.u = u; return c.h; }
__device__ __forceinline__ float fdot2(unsigned int a, hh2 b, float c) {
    return __builtin_amdgcn_fdot2(as_h2(a), b, c, false);
}
__device__ __forceinline__ float2 h2f(unsigned int u) {
    return __half22float2(*(const __half2*)&u);
}
__device__ __forceinline__ float fsig(float x) {
    return __builtin_amdgcn_rcpf(1.0f + __expf(-x));
}
__device__ __forceinline__ float ftanh(float x) {
    x = fminf(15.0f, fmaxf(-15.0f, x));
    float e = __expf(2.0f * x);
    return (e - 1.0f) * __builtin_amdgcn_rcpf(e + 1.0f);
}
// Workgroup barrier that orders LDS (lgkmcnt) but does NOT drain vmcnt:
// global loads (weights/GX, all thread-private) stay in flight across it.
__device__ __forceinline__ void light_sync() {
    asm volatile("s_waitcnt lgkmcnt(0)\n\ts_barrier" ::: "memory");
}

__global__ void prep_weights(const float* __restrict__ Wf, const float* __restrict__ Wi,
                             const float* __restrict__ Wo, const float* __restrict__ Wg,
                             const float* __restrict__ Ua, const float* __restrict__ Va,
                             unsigned char* __restrict__ ws) {
    int e = blockIdx.x * 256 + threadIdx.x;   // 0..65535
    if (e < 49152) {
        int h = e & 255, k2 = e >> 8, k = 2 * k2;
        uint4 w; __half2 t;
        t = __floats2half2_rn(Wf[h * 384 + k], Wf[h * 384 + k + 1]); w.x = *(unsigned int*)&t;
        t = __floats2half2_rn(Wi[h * 384 + k], Wi[h * 384 + k + 1]); w.y = *(unsigned int*)&t;
        t = __floats2half2_rn(Wo[h * 384 + k], Wo[h * 384 + k + 1]); w.z = *(unsigned int*)&t;
        t = __floats2half2_rn(Wg[h * 384 + k], Wg[h * 384 + k + 1]); w.w = *(unsigned int*)&t;
        ((uint4*)(ws + WP_OFF))[e] = w;
    } else {
        int e2 = e - 49152;
        const float* S = (e2 < 8192) ? Va : Ua;
        int e3 = e2 & 8191;
        int h = e3 & 255, j = e3 >> 8, k = 8 * j;
        uint4 w; __half2 t;
        t = __floats2half2_rn(S[h * 256 + k + 0], S[h * 256 + k + 1]); w.x = *(unsigned int*)&t;
        t = __floats2half2_rn(S[h * 256 + k + 2], S[h * 256 + k + 3]); w.y = *(unsigned int*)&t;
        t = __floats2half2_rn(S[h * 256 + k + 4], S[h * 256 + k + 5]); w.z = *(unsigned int*)&t;
        t = __floats2half2_rn(S[h * 256 + k + 6], S[h * 256 + k + 7]); w.w = *(unsigned int*)&t;
        ((uint4*)(ws + VAP8_OFF))[e2] = w;
    }
}

__global__ __launch_bounds__(256) void gx_gemm(const float* __restrict__ x,
                                               unsigned char* __restrict__ ws) {
    const int t = blockIdx.x, bg = blockIdx.y, tid = threadIdx.x;
    const uint4* __restrict__ WP = (const uint4*)(ws + WP_OFF);
    uint2* __restrict__ GX = (uint2*)(ws + GX_OFF);
    __shared__ float s_xx[16 * 128];
    const float* xb = x + ((size_t)t * NB + bg * 16) * NI;
#pragma unroll
    for (int r = 0; r < 8; ++r) s_xx[tid + 256 * r] = xb[tid + 256 * r];
    __syncthreads();
    const int h = tid;
    float acc[16][4];
#pragma unroll
    for (int bb = 0; bb < 16; ++bb) { acc[bb][0] = acc[bb][1] = acc[bb][2] = acc[bb][3] = 0.f; }
    for (int k2 = 128; k2 < 192; ++k2) {
        uint4 w = WP[k2 * NH + h];
        float2 wf = h2f(w.x), wi = h2f(w.y), wo = h2f(w.z), wg = h2f(w.w);
        int kk = 2 * k2 - 256;
#pragma unroll
        for (int bb = 0; bb < 16; ++bb) {
            float2 xv = *(const float2*)(s_xx + bb * 128 + kk);
            acc[bb][0] += wf.x * xv.x + wf.y * xv.y;
            acc[bb][1] += wi.x * xv.x + wi.y * xv.y;
            acc[bb][2] += wo.x * xv.x + wo.y * xv.y;
            acc[bb][3] += wg.x * xv.x + wg.y * xv.y;
        }
    }
#pragma unroll
    for (int bb = 0; bb < 16; ++bb) {
        __half2 p0 = __floats2half2_rn(acc[bb][0], acc[bb][1]);
        __half2 p1 = __floats2half2_rn(acc[bb][2], acc[bb][3]);
        uint2 u; u.x = *(unsigned int*)&p0; u.y = *(unsigned int*)&p1;
        GX[((size_t)t * NB + bg * 16 + bb) * NH + h] = u;
    }
}

// One block (1024 threads) per sample; light barriers; never-drained weight stream.
__global__ __launch_bounds__(1024, 1) void rel_lstm(
    const float* __restrict__ bf_g, const float* __restrict__ bi_g,
    const float* __restrict__ bo_g, const float* __restrict__ bg_g,
    const float* __restrict__ vv_g,
    unsigned char* __restrict__ ws, float* __restrict__ out)
{
    const int tid  = threadIdx.x;
    const int b    = blockIdx.x;
    const int role = tid >> 8;     // 0..3
    const int h    = tid & 255;

    const uint4* __restrict__ WPp = (const uint4*)(ws + WP_OFF);
    const uint4* __restrict__ VAp = (const uint4*)(ws + VAP8_OFF);
    const uint4* __restrict__ UAp = (const uint4*)(ws + UAP8_OFF);
    const uint2* __restrict__ GXp = (const uint2*)(ws + GX_OFF);

    __shared__ __align__(16) __half s_inx[NH];        // st_t (half2-packed)
    __shared__ float s_hid[NH];                       // h_{t-1} fp32
    __shared__ __align__(16) __half s_mem[LK][NH];    // hidden ring
    __shared__ __half s_memua[LK][NH + 8];            // Ua@h ring (+8 pad)
    __shared__ __half s_lraw[RS][NH];                 // long raw memory
    __shared__ __half s_luah[RS][NH + 8];             // Ua@long cache (+8 pad)
    __shared__ float s_q[NH], s_v[NH];
    __shared__ __align__(16) float s_scr[4096];       // [0..3071] gate f4 partials; [3072..4095] q/ua partials
    __shared__ float s_es[NS], s_al[NS];
    __shared__ float s_scores[T_STEPS];
    __shared__ float s_mask[RS], s_buck[RS];
    __shared__ float s_minv;
    __shared__ int s_minp, s_fill, s_upd, s_pos;

    // ---- init ----
    {
        __half z = __float2half(0.f);
#pragma unroll
        for (int j = 0; j < 4; ++j) { s_mem[role * 4 + j][h] = z; s_memua[role * 4 + j][h] = z; }
#pragma unroll
        for (int j = 0; j < 8; ++j) { s_lraw[role * 8 + j][h] = z; s_luah[role * 8 + j][h] = z; }
        if (tid < 512) s_scores[tid] = 0.f;
        s_scr[tid] = 0.f; s_scr[1024 + tid] = 0.f; s_scr[2048 + tid] = 0.f; s_scr[3072 + tid] = 0.f;
        if (tid < NH) { s_v[tid] = vv_g[tid]; s_inx[tid] = z; s_hid[tid] = 0.f; s_q[tid] = 0.f; }
        if (tid < RS) { s_mask[tid] = -1e30f; s_buck[tid] = 0.f; }
        if (tid == 0) { s_fill = 0; s_upd = 0; s_pos = 0; s_minv = 0.f; s_minp = 0; }
    }
    const float bfv = bf_g[h], biv = bi_g[h], bov = bo_g[h], bgv = bg_g[h];
    float ct = 0.f;
    int base = 0;
    uint2 gx = make_uint2(0u, 0u);
    if (tid < NH) gx = GXp[b * NH + h];
    __syncthreads();

    for (int t = 0; t < T_STEPS; ++t) {
        float4 acc = make_float4(0.f, 0.f, 0.f, 0.f);
        if (t > 0) {
            // ---- prefetch window 1: gates k2 = role*32 + [0..8) (in flight through S/X/C) ----
            uint4 bA[8];
#pragma unroll
            for (int u = 0; u < 8; ++u) bA[u] = WPp[(role * 32 + u) * NH + h];
            // ---- S: scores (48 rows x 16 lanes); argmin (wave 12); ua persist (wave 15) ----
            if (tid < 768) {
                int row = ((tid >> 6) << 2) + ((tid >> 4) & 3);
                int l = tid & 15;
                bool isShort = row < LK;
                bool newest = (row == LK - 1);
                bool skip = isShort ? (row < LK - t) : (s_mask[row - LK] < -1e29f);
                float p = -1e30f;
                if (!skip) {
                    p = 0.f;
                    if (newest) {
#pragma unroll
                        for (int j = 0; j < 16; ++j) {
                            int hh = l + (j << 4);
                            float ua = s_scr[3072 + hh] + s_scr[3328 + hh] + s_scr[3584 + hh] + s_scr[3840 + hh];
                            p += s_v[hh] * ftanh(s_q[hh] + ua);
                        }
                    } else {
                        const __half* ua = isShort ? &s_memua[(base + row) & (LK - 1)][0]
                                                   : &s_luah[row - LK][0];
#pragma unroll
                        for (int j = 0; j < 16; ++j) {
                            int hh = l + (j << 4);
                            p += s_v[hh] * ftanh(s_q[hh] + (float)ua[hh]);
                        }
                    }
                    p += __shfl_xor(p, 1, 16);
                    p += __shfl_xor(p, 2, 16);
                    p += __shfl_xor(p, 4, 16);
                    p += __shfl_xor(p, 8, 16);
                }
                if (l == 0) s_es[row] = p;
            } else if (tid < 800) {
                int l = tid - 768;
                float v = s_buck[l]; int idx = l;
#pragma unroll
                for (int off = 1; off < 32; off <<= 1) {
                    float v2 = __shfl_xor(v, off, 32);
                    int  i2 = __shfl_xor(idx, off, 32);
                    if (v2 < v || (v2 == v && i2 < idx)) { v = v2; idx = i2; }
                }
                if (l == 0) { s_minv = v; s_minp = idx; }
            } else if (tid >= 960) {
                int l = tid - 960;
                int newest = (base + LK - 1) & (LK - 1);
#pragma unroll
                for (int u = 0; u < 4; ++u) {
                    int hh = 4 * l + u;
                    float ua = s_scr[3072 + hh] + s_scr[3328 + hh] + s_scr[3584 + hh] + s_scr[3840 + hh];
                    s_memua[newest][hh] = __float2half(ua);
                }
            }
            light_sync();
            // ---- X: softmax over 48 (wave 0) ----
            if (tid < 64) {
                float e = (tid < NS) ? s_es[tid] : -1e30f;
                float m = e;
                for (int off = 32; off; off >>= 1) m = fmaxf(m, __shfl_xor(m, off));
                float a = (tid < NS) ? __expf(e - m) : 0.f;
                float ssum = a;
                for (int off = 32; off; off >>= 1) ssum += __shfl_xor(ssum, off);
                if (tid < NS) s_al[tid] = a * __builtin_amdgcn_rcpf(ssum);
            }
            light_sync();
            // ---- C: full ct_att + st (tid<256); score accum + bucket decision (wave 4) ----
            if (tid < 256) {
                float catt = 0.f;
#pragma unroll
                for (int n = 0; n < LK; ++n) catt += s_al[n] * (float)s_mem[(base + n) & (LK - 1)][h];
#pragma unroll
                for (int n = 0; n < RS; ++n) catt += s_al[LK + n] * (float)s_lraw[n][h];
                s_inx[h] = __float2half(0.5f * (s_hid[h] + catt));
            } else if (tid > 256 && tid < 256 + LK) {
                int j = tid - 256;
                int time = t - LK + j;
                if (time >= 0) s_scores[time] += s_al[j];
            } else if (tid == 256) {
                int upd = 0, pos = 0;
                if (t >= LK) {
                    float cs = s_scores[t - LK] + s_al[0];
                    s_scores[t - LK] = cs;
                    int fill = s_fill;
                    bool full = fill >= RS;
                    upd = (!full) || (cs > s_minv);
                    pos = full ? s_minp : fill;
                    if (upd) { s_mask[pos] = 0.f; s_buck[pos] = cs; if (!full) s_fill = fill + 1; }
                }
                s_upd = upd; s_pos = pos;
            }
            light_sync();
            // ---- A: gates(st_t) + q = Va@st_t; two rolling 8-deep windows, never drained ----
            {
                const unsigned int* st2 = (const unsigned int*)s_inx;
                uint4 bB[8];
#pragma unroll
                for (int u = 0; u < 8; ++u) bB[u] = WPp[(role * 32 + 8 + u) * NH + h];
#pragma unroll
                for (int u = 0; u < 8; ++u) {          // consume gates 0..7
                    hh2 s = as_h2(st2[role * 32 + u]);
                    acc.x = fdot2(bA[u].x, s, acc.x);
                    acc.y = fdot2(bA[u].y, s, acc.y);
                    acc.z = fdot2(bA[u].z, s, acc.z);
                    acc.w = fdot2(bA[u].w, s, acc.w);
                }
#pragma unroll
                for (int u = 0; u < 8; ++u) bA[u] = WPp[(role * 32 + 16 + u) * NH + h];
#pragma unroll
                for (int u = 0; u < 8; ++u) {          // consume gates 8..15
                    hh2 s = as_h2(st2[role * 32 + 8 + u]);
                    acc.x = fdot2(bB[u].x, s, acc.x);
                    acc.y = fdot2(bB[u].y, s, acc.y);
                    acc.z = fdot2(bB[u].z, s, acc.z);
                    acc.w = fdot2(bB[u].w, s, acc.w);
                }
#pragma unroll
                for (int u = 0; u < 8; ++u) bB[u] = WPp[(role * 32 + 24 + u) * NH + h];
#pragma unroll
                for (int u = 0; u < 8; ++u) {          // consume gates 16..23
                    hh2 s = as_h2(st2[role * 32 + 16 + u]);
                    acc.x = fdot2(bA[u].x, s, acc.x);
                    acc.y = fdot2(bA[u].y, s, acc.y);
                    acc.z = fdot2(bA[u].z, s, acc.z);
                    acc.w = fdot2(bA[u].w, s, acc.w);
                }
#pragma unroll
                for (int u = 0; u < 8; ++u) bA[u] = VAp[(role * 8 + u) * NH + h];
#pragma unroll
                for (int u = 0; u < 8; ++u) {          // consume gates 24..31
                    hh2 s = as_h2(st2[role * 32 + 24 + u]);
                    acc.x = fdot2(bB[u].x, s, acc.x);
                    acc.y = fdot2(bB[u].y, s, acc.y);
                    acc.z = fdot2(bB[u].z, s, acc.z);
                    acc.w = fdot2(bB[u].w, s, acc.w);
                }
                float pq = 0.f;
#pragma unroll
                for (int u = 0; u < 8; ++u) {          // consume Va
                    int j = role * 8 + u;
                    pq = fdot2(bA[u].x, as_h2(st2[4 * j + 0]), pq);
                    pq = fdot2(bA[u].y, as_h2(st2[4 * j + 1]), pq);
                    pq = fdot2(bA[u].z, as_h2(st2[4 * j + 2]), pq);
                    pq = fdot2(bA[u].w, as_h2(st2[4 * j + 3]), pq);
                }
                s_scr[3072 + role * 256 + h] = pq;
                if (role > 0) ((float4*)s_scr)[(role - 1) * 256 + h] = acc;
            }
            light_sync();
        }
        // ---- F: issue Ua prefetch; evict + combine gates + act + ring push; q combine ----
        uint4 bU[8];
#pragma unroll
        for (int u = 0; u < 8; ++u) bU[u] = UAp[(role * 8 + u) * NH + h];
        if (tid < 256) {
            int p0 = base & (LK - 1);
            if (s_upd) {
                s_lraw[s_pos][h] = s_mem[p0][h];
                s_luah[s_pos][h] = s_memua[p0][h];
            }
            const float4* s4 = (const float4*)s_scr;
            float4 B4 = s4[h], C4 = s4[256 + h], D4 = s4[512 + h];
            float2 fi = h2f(gx.x), og = h2f(gx.y);
            float f  = fsig(acc.x + B4.x + C4.x + D4.x + fi.x + bfv);
            float ii = fsig(acc.y + B4.y + C4.y + D4.y + fi.y + biv);
            float o  = fsig(acc.z + B4.z + C4.z + D4.z + og.x + bov);
            float g  = ftanh(acc.w + B4.w + C4.w + D4.w + og.y + bgv);
            ct = f * ct + ii * g;
            float hid = o * ftanh(ct);
            out[((size_t)t * NB + b) * NH + h] = hid;
            s_hid[h] = hid;
            s_mem[p0][h] = __float2half(hid);
            if (t + 1 < T_STEPS) gx = GXp[((size_t)(t + 1) * NB + b) * NH + h];
        } else if (tid < 512) {
            s_q[h] = s_scr[3072 + h] + s_scr[3328 + h] + s_scr[3584 + h] + s_scr[3840 + h];
        }
        light_sync();
        // ---- B: ua = Ua@h_t partials; combine folded into next S ----
        {
            const unsigned int* hm2 = (const unsigned int*)&s_mem[base & (LK - 1)][0];
            float pu = 0.f;
#pragma unroll
            for (int u = 0; u < 8; ++u) {
                int j = role * 8 + u;
                pu = fdot2(bU[u].x, as_h2(hm2[4 * j + 0]), pu);
                pu = fdot2(bU[u].y, as_h2(hm2[4 * j + 1]), pu);
                pu = fdot2(bU[u].z, as_h2(hm2[4 * j + 2]), pu);
                pu = fdot2(bU[u].w, as_h2(hm2[4 * j + 3]), pu);
            }
            s_scr[3072 + role * 256 + h] = pu;
        }
        base++;
        light_sync();
    }
}

extern "C" void kernel_launch(void* const* d_in, const int* in_sizes, int n_in,
                              void* d_out, int out_size, void* d_ws, size_t ws_size,
                              hipStream_t stream) {
    const float* x  = (const float*)d_in[0];
    const float* Wf = (const float*)d_in[1];
    const float* bf = (const float*)d_in[2];
    const float* Wi = (const float*)d_in[3];
    const float* bi = (const float*)d_in[4];
    const float* Wo = (const float*)d_in[5];
    const float* bo = (const float*)d_in[6];
    const float* Wg = (const float*)d_in[7];
    const float* bg = (const float*)d_in[8];
    const float* Ua = (const float*)d_in[9];
    const float* Va = (const float*)d_in[10];
    const float* vv = (const float*)d_in[11];
    unsigned char* ws = (unsigned char*)d_ws;
    float* out = (float*)d_out;

    prep_weights<<<256, 256, 0, stream>>>(Wf, Wi, Wo, Wg, Ua, Va, ws);
    gx_gemm<<<dim3(T_STEPS, 4), 256, 0, stream>>>(x, ws);
    rel_lstm<<<NB, 1024, 0, stream>>>(bf, bi, bo, bg, vv, ws, out);
}